// Round 4
// baseline (312.900 us; speedup 1.0000x reference)
//
#include <hip/hip_runtime.h>
#include <math.h>

#define HWn   3136
#define Cn    256
#define KCPB  49          // 3136/64 k-chunks per batch image
#define NCHUNK 3136       // 64 batches * 49 chunks
#define INV_M (1.0f/200704.0f)
#define EPSc  1e-5f

typedef __attribute__((ext_vector_type(4))) float f32x4;
typedef __attribute__((ext_vector_type(8))) short s16x8;
typedef __attribute__((ext_vector_type(4))) unsigned short u16x4;

static __device__ __forceinline__ unsigned short f2bf(float f) {
  unsigned int u = __builtin_bit_cast(unsigned int, f);
  u = (u + 0x7fffu + ((u >> 16) & 1u)) >> 16;   // RNE
  return (unsigned short)u;
}

// ---------------------------------------------------------------------------
// Kernel 1: partial Gram (raw, uncentered) + per-part channel sums (Sp).
// Double-buffered LDS, T14 split (loads -> MFMA -> cvt+write -> barrier).
// No atomics -> no workspace pre-zero -> no memset node in the graph.
// ---------------------------------------------------------------------------
__global__ __launch_bounds__(1024) void k_gram(const float* __restrict__ X,
                                               float* __restrict__ Gp,
                                               float* __restrict__ Sp,
                                               int nparts) {
  __shared__ __align__(16) unsigned short lds[2][256 * 64];
  const int t = threadIdx.x, p = blockIdx.x;
  const int w = t >> 6, l = t & 63, a = l & 15, g = l >> 4;
  const int swzA = (a & 7) << 3;
  const int crow = t >> 4, sg = t & 15;      // staging: c = p4*64 + crow, s-offs = sg*4

  f32x4 acc[16];
#pragma unroll
  for (int j = 0; j < 16; ++j) acc[j] = (f32x4){0.f, 0.f, 0.f, 0.f};
  float sum4[4] = {0.f, 0.f, 0.f, 0.f};
  float vx[16];

  const int start = (int)(((long)NCHUNK * p) / nparts);
  const int end   = (int)(((long)NCHUNK * (p + 1)) / nparts);

#define G_LOADS(CH)                                                           \
  {                                                                           \
    const int b_ = (CH) / KCPB, kc_ = (CH) % KCPB;                            \
    const float* xb_ = X + (long)b_ * Cn * HWn + kc_ * 64;                    \
    _Pragma("unroll")                                                         \
    for (int p4 = 0; p4 < 4; ++p4) {                                          \
      const float4 v = *(const float4*)(xb_ + (long)(p4 * 64 + crow) * HWn + sg * 4); \
      vx[p4 * 4 + 0] = v.x; vx[p4 * 4 + 1] = v.y;                             \
      vx[p4 * 4 + 2] = v.z; vx[p4 * 4 + 3] = v.w;                             \
    }                                                                         \
  }

#define G_CVTWR(BUF)                                                          \
  {                                                                           \
    _Pragma("unroll")                                                         \
    for (int p4 = 0; p4 < 4; ++p4) {                                          \
      const int c_ = p4 * 64 + crow;                                          \
      sum4[p4] += (vx[p4 * 4 + 0] + vx[p4 * 4 + 1])                           \
                + (vx[p4 * 4 + 2] + vx[p4 * 4 + 3]);                          \
      u16x4 h;                                                                \
      h.x = f2bf(vx[p4 * 4 + 0]); h.y = f2bf(vx[p4 * 4 + 1]);                 \
      h.z = f2bf(vx[p4 * 4 + 2]); h.w = f2bf(vx[p4 * 4 + 3]);                 \
      *(u16x4*)(&lds[BUF][0] + ((c_ * 64 + sg * 4) ^ ((c_ & 7) << 3))) = h;   \
    }                                                                         \
  }

  G_LOADS(start);
  G_CVTWR(0);
  __syncthreads();

  for (int ch = start; ch < end; ++ch) {
    const int cur = (ch - start) & 1;
    if (ch + 1 < end) G_LOADS(ch + 1);
    const unsigned short* tile = &lds[cur][0];
#pragma unroll
    for (int kk = 0; kk < 64; kk += 32) {
      const s16x8 fw = *(const s16x8*)(tile + (((w * 16 + a) * 64 + kk + g * 8) ^ swzA));
#pragma unroll
      for (int j = 0; j < 16; ++j) {
        const s16x8 fj = *(const s16x8*)(tile + (((j * 16 + a) * 64 + kk + g * 8) ^ swzA));
        acc[j] = __builtin_amdgcn_mfma_f32_16x16x32_bf16(fw, fj, acc[j], 0, 0, 0);
      }
    }
    if (ch + 1 < end) G_CVTWR(cur ^ 1);
    __syncthreads();
  }
#undef G_LOADS
#undef G_CVTWR

  // ---- write partial Gram: D layout col=lane&15, row=(lane>>4)*4+reg ----
  float* gout = Gp + (long)p * 65536;
#pragma unroll
  for (int j = 0; j < 16; ++j)
#pragma unroll
    for (int r = 0; r < 4; ++r)
      gout[(16 * w + 4 * g + r) * 256 + 16 * j + a] = acc[j][r];

  // ---- channel sums: reduce over the 16 sg-lanes, store per (p,chan) ----
#pragma unroll
  for (int p4 = 0; p4 < 4; ++p4) {
    float s = sum4[p4];
    s += __shfl_xor(s, 1);
    s += __shfl_xor(s, 2);
    s += __shfl_xor(s, 4);
    s += __shfl_xor(s, 8);
    if (a == 0) Sp[(long)p * 256 + p4 * 64 + w * 4 + g] = s;
  }
}

// ---------------------------------------------------------------------------
// Kernel 2: reduce partials -> Sigma row per block; P0 = I; diag export.
// Phase A: Sp -> mean (LDS). Phase B: Gp column reduction (coalesced slabs).
// ---------------------------------------------------------------------------
__global__ __launch_bounds__(1024) void k_reduce(const float* __restrict__ Gp,
                                                 const float* __restrict__ Sp,
                                                 float* __restrict__ Sigma,
                                                 float* __restrict__ P0,
                                                 float* __restrict__ diag,
                                                 float* __restrict__ meansum,
                                                 int nparts) {
  __shared__ float red[4][256];
  __shared__ float msh[256];
  const int t = threadIdx.x, c = t & 255, g = t >> 8, j = blockIdx.x;
  const long e = (long)j * 256 + c;
  const int p0 = (nparts * g) >> 2, p1 = (nparts * (g + 1)) >> 2;

  // ---- Phase A: channel sums ----
  {
    float s = 0.f;
    for (int p = p0; p < p1; ++p) s += Sp[(long)p * 256 + c];
    red[g][c] = s;
  }
  __syncthreads();
  if (g == 0) msh[c] = (red[0][c] + red[1][c]) + (red[2][c] + red[3][c]);
  __syncthreads();

  // ---- Phase B: Gram column reduction ----
  {
    const float* gp = Gp + (long)p0 * 65536 + e;
    const int np = p1 - p0;
    float s0 = 0.f, s1 = 0.f, s2 = 0.f, s3 = 0.f;
    int p = 0;
#pragma unroll 2
    for (; p + 4 <= np; p += 4) {
      s0 += gp[(long)(p + 0) * 65536];
      s1 += gp[(long)(p + 1) * 65536];
      s2 += gp[(long)(p + 2) * 65536];
      s3 += gp[(long)(p + 3) * 65536];
    }
    for (; p < np; ++p) s0 += gp[(long)p * 65536];
    red[g][c] = (s0 + s1) + (s2 + s3);
  }
  __syncthreads();

  if (g == 0) {
    const float tot = (red[0][c] + red[1][c]) + (red[2][c] + red[3][c]);
    const float mc = msh[c] * INV_M;
    const float mj = msh[j] * INV_M;
    const float sig = tot * INV_M - mj * mc + ((j == c) ? EPSc : 0.f);
    Sigma[e] = sig;
    if (c == j) diag[j] = sig;
    if (j == 0) meansum[c] = msh[c];
  } else if (g == 1) {
    P0[e] = (j == c) ? 1.f : 0.f;
  }
}

// ---------------------------------------------------------------------------
// Kernel 3: trace -> scal[0]=tr, scal[1]=1/tr, scal[2]=sqrt(1/tr).
// ---------------------------------------------------------------------------
__global__ void k_prep(const float* __restrict__ diag, float* __restrict__ scal) {
  __shared__ float r[256];
  const int c = threadIdx.x;
  r[c] = diag[c];
  __syncthreads();
  for (int st = 128; st > 0; st >>= 1) {
    if (c < st) r[c] += r[c + st];
    __syncthreads();
  }
  if (c == 0) {
    const float tr = r[0];
    scal[0] = tr;
    scal[1] = 1.0f / tr;
    scal[2] = sqrtf(1.0f / tr);
  }
}

// ---------------------------------------------------------------------------
// Kernel 4 (x10): one Newton-Schulz step, fp32.
// 64 blocks x 1024 threads: 4 rows/block, 256 cols, split-K x4.
// ---------------------------------------------------------------------------
__global__ __launch_bounds__(1024) void k_ns(const float* __restrict__ Ps,
                                             float* __restrict__ Pd,
                                             const float* __restrict__ Sig,
                                             const float* __restrict__ scal) {
  __shared__ __align__(16) float PT[256][4];       // A-panel transposed [k][r]
  __shared__ __align__(16) float red[4][256][4];   // [kh][c][r]
  const int t = threadIdx.x, c = t & 255, kh = t >> 8, k0 = kh * 64;
  const int r0 = blockIdx.x * 4;

  PT[c][kh] = Ps[(r0 + kh) * 256 + c];
  __syncthreads();

  f32x4 acc;

#define NS_PHASE(BPTR)                                                        \
  {                                                                           \
    acc = (f32x4){0.f, 0.f, 0.f, 0.f};                                        \
    const float* Bb = (BPTR) + (long)k0 * 256 + c;                            \
    _Pragma("unroll 8")                                                       \
    for (int kk = 0; kk < 64; ++kk) {                                         \
      const float b = Bb[(long)kk * 256];                                     \
      const f32x4 a4 = *(const f32x4*)&PT[k0 + kk][0];                        \
      acc += a4 * b;                                                          \
    }                                                                         \
    *(f32x4*)&red[kh][c][0] = acc;                                            \
    __syncthreads();                                                          \
  }

#define NS_COMBINE()                                                          \
  {                                                                           \
    const f32x4 vs = (*(const f32x4*)&red[0][c][0] + *(const f32x4*)&red[1][c][0]) \
                   + (*(const f32x4*)&red[2][c][0] + *(const f32x4*)&red[3][c][0]); \
    if (kh == 0) *(f32x4*)&PT[c][0] = vs;                                     \
    __syncthreads();                                                          \
  }

  NS_PHASE(Ps);    // t1 = panel(P) * P
  NS_COMBINE();
  NS_PHASE(Ps);    // t2 = t1 * P
  NS_COMBINE();
  NS_PHASE(Sig);   // t3 = t2 * Sigma

  const float rTr = scal[1];
  const float t3 = ((red[0][c][kh] + red[1][c][kh]) + (red[2][c][kh] + red[3][c][kh]));
  const float pr = Ps[(r0 + kh) * 256 + c];
  Pd[(r0 + kh) * 256 + c] = 1.5f * pr - 0.5f * rTr * t3;
#undef NS_PHASE
#undef NS_COMBINE
}

// ---------------------------------------------------------------------------
// Kernel 5: A = sqrt(rTr) * (rot * P) -> bf16; bias = A * mean.
// ---------------------------------------------------------------------------
__global__ void k_makeA(const float* __restrict__ rot, const float* __restrict__ P,
                        const float* __restrict__ scal, const float* __restrict__ meansum,
                        unsigned short* __restrict__ Abf, float* __restrict__ bias) {
  __shared__ float Rw[8][256];
  __shared__ float Tw[8][256];
  const int r0 = blockIdx.x * 8, c = threadIdx.x;
#pragma unroll
  for (int r = 0; r < 8; ++r) Rw[r][c] = rot[(r0 + r) * 256 + c];
  __syncthreads();
  float t[8];
#pragma unroll
  for (int r = 0; r < 8; ++r) t[r] = 0.f;
  for (int k = 0; k < 256; ++k) {
    const float pv = P[k * 256 + c];
#pragma unroll
    for (int r = 0; r < 8; ++r) t[r] += Rw[r][k] * pv;
  }
  const float s = scal[2];
  const float mc = meansum[c] * INV_M;
#pragma unroll
  for (int r = 0; r < 8; ++r) {
    const float av = t[r] * s;
    Abf[(r0 + r) * 256 + c] = f2bf(av);
    Tw[r][c] = av * mc;
  }
  __syncthreads();
  for (int st = 128; st > 0; st >>= 1) {
    if (c < st) {
#pragma unroll
      for (int r = 0; r < 8; ++r) Tw[r][c] += Tw[r][c + st];
    }
    __syncthreads();
  }
  if (c == 0) {
#pragma unroll
    for (int r = 0; r < 8; ++r) bias[r0 + r] = Tw[r][0];
  }
}

// ---------------------------------------------------------------------------
// Kernel 6: out = A*x - bias. 512 blocks (64 b x 8 strips of 6-7 chunks).
// Swapped MFMA operands -> D rows = s -> float4 stores. A-frags in regs.
// Double-buffered LDS, T14 split staging.
// ---------------------------------------------------------------------------
__global__ __launch_bounds__(1024) void k_apply(const float* __restrict__ X,
                                                const unsigned short* __restrict__ Abf,
                                                const float* __restrict__ bias,
                                                float* __restrict__ out) {
  __shared__ __align__(16) unsigned short lds[2][64 * 256];
  const int t = threadIdx.x, w = t >> 6, l = t & 63, a = l & 15, g = l >> 4;
  const int bid = blockIdx.x;
  const int b = bid >> 3, strip = bid & 7;
  const int ch0 = (49 * strip) >> 3, ch1 = (49 * (strip + 1)) >> 3;

  // hoist A fragments (B-operand) + bias into registers
  const int d = 16 * w + a;
  s16x8 af[8];
#pragma unroll
  for (int kk8 = 0; kk8 < 8; ++kk8)
    af[kk8] = *(const s16x8*)(Abf + d * 256 + kk8 * 32 + g * 8);
  const float bd = bias[d];

  const float* xbase = X + (long)b * Cn * HWn;
  float* obase = out + (long)b * Cn * HWn;
  float vx[16];

#define A_LOADS(CH)                                                           \
  {                                                                           \
    const int s0_ = (CH) * 64;                                                \
    _Pragma("unroll")                                                         \
    for (int p4 = 0; p4 < 4; ++p4) {                                          \
      const int c4_ = p4 * 16 + w;                                            \
      const float* xp_ = xbase + (long)(c4_ * 4) * HWn + s0_ + l;             \
      vx[p4 * 4 + 0] = xp_[0];                                                \
      vx[p4 * 4 + 1] = xp_[HWn];                                              \
      vx[p4 * 4 + 2] = xp_[2 * HWn];                                          \
      vx[p4 * 4 + 3] = xp_[3 * HWn];                                          \
    }                                                                         \
  }

#define A_CVTWR(BUF)                                                          \
  {                                                                           \
    _Pragma("unroll")                                                         \
    for (int p4 = 0; p4 < 4; ++p4) {                                          \
      const int c4_ = p4 * 16 + w;                                            \
      u16x4 h;                                                                \
      h.x = f2bf(vx[p4 * 4 + 0]); h.y = f2bf(vx[p4 * 4 + 1]);                 \
      h.z = f2bf(vx[p4 * 4 + 2]); h.w = f2bf(vx[p4 * 4 + 3]);                 \
      *(u16x4*)(&lds[BUF][0] + ((l * 256 + c4_ * 4) ^ ((l & 7) << 3))) = h;   \
    }                                                                         \
  }

  A_LOADS(ch0);
  A_CVTWR(0);
  __syncthreads();

  for (int ch = ch0; ch < ch1; ++ch) {
    const int cur = (ch - ch0) & 1;
    if (ch + 1 < ch1) A_LOADS(ch + 1);

    const unsigned short* tile = &lds[cur][0];
    f32x4 acc[4];
#pragma unroll
    for (int st = 0; st < 4; ++st) acc[st] = (f32x4){0.f, 0.f, 0.f, 0.f};
#pragma unroll
    for (int kk8 = 0; kk8 < 8; ++kk8) {
#pragma unroll
      for (int st = 0; st < 4; ++st) {
        const s16x8 xf = *(const s16x8*)(tile + (((st * 16 + a) * 256 + kk8 * 32 + g * 8) ^ ((a & 7) << 3)));
        acc[st] = __builtin_amdgcn_mfma_f32_16x16x32_bf16(xf, af[kk8], acc[st], 0, 0, 0);
      }
    }
    // store: lane (a,g) holds s = st*16 + 4g + r  -> float4 per st
    const int s0 = ch * 64;
#pragma unroll
    for (int st = 0; st < 4; ++st) {
      const f32x4 o = acc[st] - bd;
      *(f32x4*)(obase + (long)d * HWn + s0 + st * 16 + 4 * g) = o;
    }

    if (ch + 1 < ch1) A_CVTWR(cur ^ 1);
    __syncthreads();
  }
#undef A_LOADS
#undef A_CVTWR
}

// ---------------------------------------------------------------------------
extern "C" void kernel_launch(void* const* d_in, const int* in_sizes, int n_in,
                              void* d_out, int out_size, void* d_ws, size_t ws_size,
                              hipStream_t stream) {
  const float* X = (const float*)d_in[0];
  const float* rot = (const float*)d_in[1];
  float* out = (float*)d_out;

  auto need = [](int np) -> size_t {
    return (size_t)4 * ((size_t)np * 65536 + (size_t)np * 256 + 3 * 65536
                        + 256 + 256 + 16 + 256)
         + (size_t)2 * 65536;
  };
  int nparts = 256;
  while (nparts > 4 && need(nparts) > ws_size) nparts >>= 1;

  float* w = (float*)d_ws;
  float* Gp = w;       w += (size_t)nparts * 65536;
  float* Sp = w;       w += (size_t)nparts * 256;
  float* Sigma = w;    w += 65536;
  float* P0 = w;       w += 65536;
  float* P1 = w;       w += 65536;
  float* diag = w;     w += 256;
  float* meansum = w;  w += 256;
  float* scal = w;     w += 16;
  float* bias = w;     w += 256;
  unsigned short* Abf = (unsigned short*)w;

  k_gram<<<dim3(nparts), dim3(1024), 0, stream>>>(X, Gp, Sp, nparts);
  k_reduce<<<dim3(256), dim3(1024), 0, stream>>>(Gp, Sp, Sigma, P0, diag, meansum, nparts);
  k_prep<<<dim3(1), dim3(256), 0, stream>>>(diag, scal);
  float* ps = P0;
  float* pd = P1;
  for (int i = 0; i < 10; ++i) {
    k_ns<<<dim3(64), dim3(1024), 0, stream>>>(ps, pd, Sigma, scal);
    float* tmp = ps; ps = pd; pd = tmp;
  }
  k_makeA<<<dim3(32), dim3(256), 0, stream>>>(rot, ps, scal, meansum, Abf, bias);
  k_apply<<<dim3(512), dim3(1024), 0, stream>>>(X, Abf, bias, out);
}